// Round 3
// baseline (2665.457 us; speedup 1.0000x reference)
//
#include <hip/hip_runtime.h>

#define CH 64
#define BNODES 128           // nodes per bucket (dst >> 7)
#define NB_MAX 1024

// ---------------- GEMM: out[n][64] = (relu?)(h[n][K]) @ W[K][64] ----------------
template<int K, bool RELU>
__global__ __launch_bounds__(256) void gemm_kernel(
    const float* __restrict__ h, const float* __restrict__ W,
    float* __restrict__ out, int n)
{
    constexpr int LDH = K + 4;
    __shared__ float Ws[K * CH];
    __shared__ float Hs[64 * LDH];

    const int t    = threadIdx.x;
    const int row0 = blockIdx.x * 64;

    for (int i = t * 4; i < K * CH; i += 256 * 4) {
        *(float4*)&Ws[i] = *(const float4*)&W[i];
    }
    for (int i = t * 4; i < 64 * K; i += 256 * 4) {
        int r = i / K;
        int k = i % K;
        int row = row0 + r;
        float4 v;
        if (row < n) {
            v = *(const float4*)&h[(size_t)row * K + k];
            if (RELU) {
                v.x = fmaxf(v.x, 0.f); v.y = fmaxf(v.y, 0.f);
                v.z = fmaxf(v.z, 0.f); v.w = fmaxf(v.w, 0.f);
            }
        } else {
            v = make_float4(0.f, 0.f, 0.f, 0.f);
        }
        *(float4*)&Hs[r * LDH + k] = v;
    }
    __syncthreads();

    const int cg = t & 15;
    const int rq = t >> 4;

    float4 acc[4];
    #pragma unroll
    for (int i = 0; i < 4; ++i) acc[i] = make_float4(0.f, 0.f, 0.f, 0.f);

    for (int k = 0; k < K; k += 4) {
        float4 w[4];
        #pragma unroll
        for (int kk = 0; kk < 4; ++kk)
            w[kk] = *(float4*)&Ws[(k + kk) * CH + cg * 4];
        #pragma unroll
        for (int i = 0; i < 4; ++i) {
            float4 hv = *(float4*)&Hs[(rq * 4 + i) * LDH + k];
            float hs[4] = {hv.x, hv.y, hv.z, hv.w};
            #pragma unroll
            for (int kk = 0; kk < 4; ++kk) {
                acc[i].x = fmaf(hs[kk], w[kk].x, acc[i].x);
                acc[i].y = fmaf(hs[kk], w[kk].y, acc[i].y);
                acc[i].z = fmaf(hs[kk], w[kk].z, acc[i].z);
                acc[i].w = fmaf(hs[kk], w[kk].w, acc[i].w);
            }
        }
    }

    #pragma unroll
    for (int i = 0; i < 4; ++i) {
        int row = row0 + rq * 4 + i;
        if (row < n)
            *(float4*)&out[(size_t)row * CH + cg * 4] = acc[i];
    }
}

// ---------------- bucket histogram: bcnt[b] = #edges with dst>>7 == b ----------------
__global__ __launch_bounds__(256) void bucket_hist(
    const int* __restrict__ dst, int* __restrict__ bcnt, int E, int NB)
{
    __shared__ int h[NB_MAX];
    for (int i = threadIdx.x; i < NB; i += 256) h[i] = 0;
    __syncthreads();
    for (int i = blockIdx.x * 256 + threadIdx.x; i < E; i += gridDim.x * 256)
        atomicAdd(&h[dst[i] >> 7], 1);
    __syncthreads();
    for (int i = threadIdx.x; i < NB; i += 256) {
        int v = h[i];
        if (v) atomicAdd(&bcnt[i], v);
    }
}

// ---------------- single-block exclusive scan over NB (<=1024) counts ----------------
__global__ __launch_bounds__(256) void bucket_scan(
    const int* __restrict__ bcnt, int* __restrict__ boff,
    int* __restrict__ cursor, int NB)
{
    __shared__ int tsum[256];
    int t = threadIdx.x;
    int base = t * 4;
    int c[4];
    #pragma unroll
    for (int j = 0; j < 4; ++j) {
        int i = base + j;
        c[j] = (i < NB) ? bcnt[i] : 0;
    }
    int local = c[0] + c[1] + c[2] + c[3];
    tsum[t] = local;
    __syncthreads();
    for (int off = 1; off < 256; off <<= 1) {
        int v = (t >= off) ? tsum[t - off] : 0;
        __syncthreads();
        tsum[t] += v;
        __syncthreads();
    }
    int p = tsum[t] - local;
    #pragma unroll
    for (int j = 0; j < 4; ++j) {
        int i = base + j;
        if (i < NB) { boff[i] = p; cursor[i] = p; }
        p += c[j];
    }
    if (t == 255) boff[NB] = tsum[255];
}

// ---------------- append edges into bucket-major packed list ----------------
// packed = ((dst & 127) << 17) | src     (src < 2^17)
__global__ __launch_bounds__(256) void bucket_scatter(
    const int* __restrict__ src, const int* __restrict__ dst,
    int* __restrict__ cursor, int* __restrict__ bucketed, int E)
{
    int e = blockIdx.x * 256 + threadIdx.x;
    if (e >= E) return;
    int d = dst[e];
    int p = atomicAdd(&cursor[d >> 7], 1);
    bucketed[p] = ((d & 127) << 17) | src[e];
}

// ---------------- aggregate: one block per bucket, LDS accumulator ----------------
// out[node][c] = b[c] + sum over edges of hw[src][c]
__global__ __launch_bounds__(256) void aggregate_kernel(
    const float* __restrict__ hw, const int* __restrict__ bucketed,
    const int* __restrict__ boff, const float* __restrict__ bias,
    float* __restrict__ out, int N)
{
    __shared__ float acc[BNODES * CH];           // 32 KB
    const int t    = threadIdx.x;
    const int lane = t & 63;
    const int wid  = t >> 6;
    const int bk   = blockIdx.x;

    #pragma unroll
    for (int i = t * 4; i < BNODES * CH; i += 1024)
        *(float4*)&acc[i] = make_float4(0.f, 0.f, 0.f, 0.f);
    __syncthreads();

    const int segs = boff[bk];
    const int sege = boff[bk + 1];

    for (int base = segs + wid * 64; base < sege; base += 256) {
        int navail = sege - base;
        if (navail >= 64) {
            int my = bucketed[base + lane];
            #pragma unroll 8
            for (int j = 0; j < 64; ++j) {
                int p   = __shfl(my, j);
                int s   = p & 0x1FFFF;
                int dl  = p >> 17;
                atomicAdd(&acc[dl * CH + lane], hw[(size_t)s * CH + lane]);
            }
        } else {
            int my = (lane < navail) ? bucketed[base + lane] : 0;
            for (int j = 0; j < navail; ++j) {
                int p   = __shfl(my, j);
                int s   = p & 0x1FFFF;
                int dl  = p >> 17;
                atomicAdd(&acc[dl * CH + lane], hw[(size_t)s * CH + lane]);
            }
        }
    }
    __syncthreads();

    // epilogue: add bias, coalesced store. 128 nodes x 16 float4.
    const int node0 = bk * BNODES;
    for (int i = t; i < BNODES * (CH / 4); i += 256) {
        int node = node0 + (i >> 4);
        if (node < N) {
            float4 v  = *(float4*)&acc[i * 4];
            float4 bv = *(const float4*)&bias[(i & 15) * 4];
            v.x += bv.x; v.y += bv.y; v.z += bv.z; v.w += bv.w;
            *(float4*)&out[(size_t)node * CH + (i & 15) * 4] = v;
        }
    }
}

extern "C" void kernel_launch(void* const* d_in, const int* in_sizes, int n_in,
                              void* d_out, int out_size, void* d_ws, size_t ws_size,
                              hipStream_t stream) {
    const float* x    = (const float*)d_in[0];
    const int*   esrc = (const int*)  d_in[1];
    const int*   edst = (const int*)  d_in[2];
    const float* W1   = (const float*)d_in[3];
    const float* b1   = (const float*)d_in[4];
    const float* W2   = (const float*)d_in[5];
    const float* b2   = (const float*)d_in[6];
    const float* W3   = (const float*)d_in[7];
    const float* b3   = (const float*)d_in[8];
    float* out = (float*)d_out;

    const int N  = in_sizes[0] / 128;
    const int E  = in_sizes[1];
    const int NB = (N + BNODES - 1) / BNODES;   // 782 for N=100000

    // workspace layout
    char* ws = (char*)d_ws;
    float* buf0     = (float*)ws;  ws += (size_t)N * CH * 4;   // hw
    int*   bucketed = (int*)ws;    ws += (size_t)E * 4;
    int*   bcnt     = (int*)ws;    ws += (size_t)NB * 4;
    int*   boff     = (int*)ws;    ws += (size_t)(NB + 1) * 4;
    int*   cursor   = (int*)ws;    ws += (size_t)NB * 4;

    dim3 blk(256);
    int gemmGrid = (N + 63) / 64;
    int edgeGrid = (E + 255) / 256;

    // ---- bucket build (once; shared by all 3 layers) ----
    hipMemsetAsync(bcnt, 0, (size_t)NB * 4, stream);
    bucket_hist<<<256, blk, 0, stream>>>(edst, bcnt, E, NB);
    bucket_scan<<<1, blk, 0, stream>>>(bcnt, boff, cursor, NB);
    bucket_scatter<<<edgeGrid, blk, 0, stream>>>(esrc, edst, cursor, bucketed, E);

    // ---- layer 1 ----
    gemm_kernel<128, false><<<gemmGrid, blk, 0, stream>>>(x, W1, buf0, N);
    aggregate_kernel<<<NB, blk, 0, stream>>>(buf0, bucketed, boff, b1, out, N);
    // ---- layer 2 (relu fused into gemm load) ----
    gemm_kernel<64, true><<<gemmGrid, blk, 0, stream>>>(out, W2, buf0, N);
    aggregate_kernel<<<NB, blk, 0, stream>>>(buf0, bucketed, boff, b2, out, N);
    // ---- layer 3 ----
    gemm_kernel<64, true><<<gemmGrid, blk, 0, stream>>>(out, W3, buf0, N);
    aggregate_kernel<<<NB, blk, 0, stream>>>(buf0, bucketed, boff, b3, out, N);
}

// Round 4
// 758.313 us; speedup vs baseline: 3.5150x; 3.5150x over previous
//
#include <hip/hip_runtime.h>

#define CH 64
#define BNODES 128           // nodes per bucket (dst >> 7)
#define NB_MAX 1024

// ---------------- GEMM: out[n][64] = (relu?)(h[n][K]) @ W[K][64] ----------------
template<int K, bool RELU>
__global__ __launch_bounds__(256) void gemm_kernel(
    const float* __restrict__ h, const float* __restrict__ W,
    float* __restrict__ out, int n)
{
    constexpr int LDH = K + 4;
    __shared__ float Ws[K * CH];
    __shared__ float Hs[64 * LDH];

    const int t    = threadIdx.x;
    const int row0 = blockIdx.x * 64;

    for (int i = t * 4; i < K * CH; i += 256 * 4) {
        *(float4*)&Ws[i] = *(const float4*)&W[i];
    }
    for (int i = t * 4; i < 64 * K; i += 256 * 4) {
        int r = i / K;
        int k = i % K;
        int row = row0 + r;
        float4 v;
        if (row < n) {
            v = *(const float4*)&h[(size_t)row * K + k];
            if (RELU) {
                v.x = fmaxf(v.x, 0.f); v.y = fmaxf(v.y, 0.f);
                v.z = fmaxf(v.z, 0.f); v.w = fmaxf(v.w, 0.f);
            }
        } else {
            v = make_float4(0.f, 0.f, 0.f, 0.f);
        }
        *(float4*)&Hs[r * LDH + k] = v;
    }
    __syncthreads();

    const int cg = t & 15;
    const int rq = t >> 4;

    float4 acc[4];
    #pragma unroll
    for (int i = 0; i < 4; ++i) acc[i] = make_float4(0.f, 0.f, 0.f, 0.f);

    for (int k = 0; k < K; k += 4) {
        float4 w[4];
        #pragma unroll
        for (int kk = 0; kk < 4; ++kk)
            w[kk] = *(float4*)&Ws[(k + kk) * CH + cg * 4];
        #pragma unroll
        for (int i = 0; i < 4; ++i) {
            float4 hv = *(float4*)&Hs[(rq * 4 + i) * LDH + k];
            float hs[4] = {hv.x, hv.y, hv.z, hv.w};
            #pragma unroll
            for (int kk = 0; kk < 4; ++kk) {
                acc[i].x = fmaf(hs[kk], w[kk].x, acc[i].x);
                acc[i].y = fmaf(hs[kk], w[kk].y, acc[i].y);
                acc[i].z = fmaf(hs[kk], w[kk].z, acc[i].z);
                acc[i].w = fmaf(hs[kk], w[kk].w, acc[i].w);
            }
        }
    }

    #pragma unroll
    for (int i = 0; i < 4; ++i) {
        int row = row0 + rq * 4 + i;
        if (row < n)
            *(float4*)&out[(size_t)row * CH + cg * 4] = acc[i];
    }
}

// ---------------- bucket histogram (LDS-staged) ----------------
__global__ __launch_bounds__(256) void bucket_hist(
    const int* __restrict__ dst, int* __restrict__ bcnt, int E, int NB)
{
    __shared__ int h[NB_MAX];
    for (int i = threadIdx.x; i < NB; i += 256) h[i] = 0;
    __syncthreads();
    for (int i = blockIdx.x * 256 + threadIdx.x; i < E; i += gridDim.x * 256)
        atomicAdd(&h[dst[i] >> 7], 1);
    __syncthreads();
    for (int i = threadIdx.x; i < NB; i += 256) {
        int v = h[i];
        if (v) atomicAdd(&bcnt[i], v);
    }
}

// ---------------- single-block exclusive scan over NB (<=1024) counts ----------------
__global__ __launch_bounds__(256) void bucket_scan(
    const int* __restrict__ bcnt, int* __restrict__ boff,
    int* __restrict__ cursor, int NB)
{
    __shared__ int tsum[256];
    int t = threadIdx.x;
    int base = t * 4;
    int c[4];
    #pragma unroll
    for (int j = 0; j < 4; ++j) {
        int i = base + j;
        c[j] = (i < NB) ? bcnt[i] : 0;
    }
    int local = c[0] + c[1] + c[2] + c[3];
    tsum[t] = local;
    __syncthreads();
    for (int off = 1; off < 256; off <<= 1) {
        int v = (t >= off) ? tsum[t - off] : 0;
        __syncthreads();
        tsum[t] += v;
        __syncthreads();
    }
    int p = tsum[t] - local;
    #pragma unroll
    for (int j = 0; j < 4; ++j) {
        int i = base + j;
        if (i < NB) { boff[i] = p; cursor[i] = p; }
        p += c[j];
    }
    if (t == 255) boff[NB] = tsum[255];
}

// ---------------- append edges into bucket-major packed list ----------------
// packed = ((dst & 127) << 17) | src     (src < 2^17)
__global__ __launch_bounds__(256) void bucket_scatter(
    const int* __restrict__ src, const int* __restrict__ dst,
    int* __restrict__ cursor, int* __restrict__ bucketed, int E)
{
    int e = blockIdx.x * 256 + threadIdx.x;
    if (e >= E) return;
    int d = dst[e];
    int p = atomicAdd(&cursor[d >> 7], 1);
    bucketed[p] = ((d & 127) << 17) | src[e];
}

// ---------------- per-bucket counting sort -> per-node CSR segments ----------------
// one block per bucket; all writes land in the bucket's contiguous output region
__global__ __launch_bounds__(256) void node_sort(
    const int* __restrict__ bucketed, const int* __restrict__ boff,
    int* __restrict__ sorted_src, int2* __restrict__ seg, int N)
{
    __shared__ int cnt[BNODES];
    __shared__ int sc[BNODES];
    __shared__ int cur[BNODES];
    const int bk = blockIdx.x;
    const int t  = threadIdx.x;
    const int s  = boff[bk];
    const int e  = boff[bk + 1];

    if (t < BNODES) cnt[t] = 0;
    __syncthreads();
    for (int i = s + t; i < e; i += 256)
        atomicAdd(&cnt[((unsigned)bucketed[i]) >> 17], 1);
    __syncthreads();

    // inclusive scan of cnt (128 entries) via Hillis-Steele in LDS
    if (t < BNODES) sc[t] = cnt[t];
    __syncthreads();
    for (int o = 1; o < BNODES; o <<= 1) {
        int v = (t < BNODES && t >= o) ? sc[t - o] : 0;
        __syncthreads();
        if (t < BNODES) sc[t] += v;
        __syncthreads();
    }
    // exclusive offsets + seg descriptors + running cursors
    if (t < BNODES) {
        int excl = sc[t] - cnt[t];
        cur[t] = excl;
        int node = bk * BNODES + t;
        if (node < N) seg[node] = make_int2(s + excl, cnt[t]);
    }
    __syncthreads();

    // pass 2: place each edge's src at its sorted position
    for (int i = s + t; i < e; i += 256) {
        int p = bucketed[i];
        int d = ((unsigned)p) >> 17;
        int pos = atomicAdd(&cur[d], 1);
        sorted_src[s + pos] = p & 0x1FFFF;
    }
}

// ---------------- aggregate: out[d][c] = b[c] + sum_{e in seg(d)} hw[src[e]][c] ----------------
// one wave per node; indices broadcast via shfl; 8 gathers in flight
__global__ __launch_bounds__(256) void aggregate_kernel(
    const float* __restrict__ hw, const int* __restrict__ sorted_src,
    const int2* __restrict__ seg, const float* __restrict__ bias,
    float* __restrict__ out, int N)
{
    const int lane = threadIdx.x & 63;
    const int node = blockIdx.x * 4 + (threadIdx.x >> 6);
    if (node >= N) return;

    int2 sc   = seg[node];
    int  base = sc.x;
    int  rem  = sc.y;

    float a[8];
    a[0] = bias[lane];
    #pragma unroll
    for (int i = 1; i < 8; ++i) a[i] = 0.f;

    while (rem > 0) {
        int take = rem < 64 ? rem : 64;
        int my = (lane < take) ? sorted_src[base + lane] : 0;
        int j = 0;
        for (; j + 8 <= take; j += 8) {
            int idx[8];
            #pragma unroll
            for (int u = 0; u < 8; ++u) idx[u] = __shfl(my, j + u);
            #pragma unroll
            for (int u = 0; u < 8; ++u)
                a[u] += hw[(size_t)idx[u] * CH + lane];
        }
        for (; j < take; ++j)
            a[0] += hw[(size_t)__shfl(my, j) * CH + lane];
        base += take;
        rem  -= take;
    }

    float r = ((a[0] + a[1]) + (a[2] + a[3])) + ((a[4] + a[5]) + (a[6] + a[7]));
    out[(size_t)node * CH + lane] = r;
}

extern "C" void kernel_launch(void* const* d_in, const int* in_sizes, int n_in,
                              void* d_out, int out_size, void* d_ws, size_t ws_size,
                              hipStream_t stream) {
    const float* x    = (const float*)d_in[0];
    const int*   esrc = (const int*)  d_in[1];
    const int*   edst = (const int*)  d_in[2];
    const float* W1   = (const float*)d_in[3];
    const float* b1   = (const float*)d_in[4];
    const float* W2   = (const float*)d_in[5];
    const float* b2   = (const float*)d_in[6];
    const float* W3   = (const float*)d_in[7];
    const float* b3   = (const float*)d_in[8];
    float* out = (float*)d_out;

    const int N  = in_sizes[0] / 128;
    const int E  = in_sizes[1];
    const int NB = (N + BNODES - 1) / BNODES;   // 782 for N=100000

    // workspace layout (~39.6 MB)
    char* ws = (char*)d_ws;
    float* buf0       = (float*)ws;  ws += (size_t)N * CH * 4;   // hw
    int*   bucketed   = (int*)ws;    ws += (size_t)E * 4;
    int*   sorted_src = (int*)ws;    ws += (size_t)E * 4;
    int2*  seg        = (int2*)ws;   ws += (size_t)N * 8;
    int*   bcnt       = (int*)ws;    ws += (size_t)NB * 4;
    int*   boff       = (int*)ws;    ws += (size_t)(NB + 1) * 4;
    int*   cursor     = (int*)ws;    ws += (size_t)NB * 4;

    dim3 blk(256);
    int gemmGrid = (N + 63) / 64;
    int aggGrid  = (N + 3) / 4;
    int edgeGrid = (E + 255) / 256;

    // ---- CSR build via buckets (once; shared by all 3 layers) ----
    hipMemsetAsync(bcnt, 0, (size_t)NB * 4, stream);
    bucket_hist<<<256, blk, 0, stream>>>(edst, bcnt, E, NB);
    bucket_scan<<<1, blk, 0, stream>>>(bcnt, boff, cursor, NB);
    bucket_scatter<<<edgeGrid, blk, 0, stream>>>(esrc, edst, cursor, bucketed, E);
    node_sort<<<NB, blk, 0, stream>>>(bucketed, boff, sorted_src, seg, N);

    // ---- layer 1 ----
    gemm_kernel<128, false><<<gemmGrid, blk, 0, stream>>>(x, W1, buf0, N);
    aggregate_kernel<<<aggGrid, blk, 0, stream>>>(buf0, sorted_src, seg, b1, out, N);
    // ---- layer 2 (relu fused into gemm load) ----
    gemm_kernel<64, true><<<gemmGrid, blk, 0, stream>>>(out, W2, buf0, N);
    aggregate_kernel<<<aggGrid, blk, 0, stream>>>(buf0, sorted_src, seg, b2, out, N);
    // ---- layer 3 ----
    gemm_kernel<64, true><<<gemmGrid, blk, 0, stream>>>(out, W3, buf0, N);
    aggregate_kernel<<<aggGrid, blk, 0, stream>>>(buf0, sorted_src, seg, b3, out, N);
}

// Round 5
// 422.067 us; speedup vs baseline: 6.3152x; 1.7967x over previous
//
#include <hip/hip_runtime.h>

#define CH 64
#define BNODES 128           // nodes per bucket (dst >> 7)
#define NB_MAX 1024
#define CUR_PAD 16           // cursor padding: 16 ints = 64 B = own cache line
#define SCAT_CHUNK 8192      // edges per scatter block

// ---------------- GEMM: out[n][64] = (relu?)(h[n][K]) @ W[K][64] ----------------
template<int K, bool RELU>
__global__ __launch_bounds__(256) void gemm_kernel(
    const float* __restrict__ h, const float* __restrict__ W,
    float* __restrict__ out, int n)
{
    constexpr int LDH = K + 4;
    __shared__ float Ws[K * CH];
    __shared__ float Hs[64 * LDH];

    const int t    = threadIdx.x;
    const int row0 = blockIdx.x * 64;

    for (int i = t * 4; i < K * CH; i += 256 * 4) {
        *(float4*)&Ws[i] = *(const float4*)&W[i];
    }
    for (int i = t * 4; i < 64 * K; i += 256 * 4) {
        int r = i / K;
        int k = i % K;
        int row = row0 + r;
        float4 v;
        if (row < n) {
            v = *(const float4*)&h[(size_t)row * K + k];
            if (RELU) {
                v.x = fmaxf(v.x, 0.f); v.y = fmaxf(v.y, 0.f);
                v.z = fmaxf(v.z, 0.f); v.w = fmaxf(v.w, 0.f);
            }
        } else {
            v = make_float4(0.f, 0.f, 0.f, 0.f);
        }
        *(float4*)&Hs[r * LDH + k] = v;
    }
    __syncthreads();

    const int cg = t & 15;
    const int rq = t >> 4;

    float4 acc[4];
    #pragma unroll
    for (int i = 0; i < 4; ++i) acc[i] = make_float4(0.f, 0.f, 0.f, 0.f);

    for (int k = 0; k < K; k += 4) {
        float4 w[4];
        #pragma unroll
        for (int kk = 0; kk < 4; ++kk)
            w[kk] = *(float4*)&Ws[(k + kk) * CH + cg * 4];
        #pragma unroll
        for (int i = 0; i < 4; ++i) {
            float4 hv = *(float4*)&Hs[(rq * 4 + i) * LDH + k];
            float hs[4] = {hv.x, hv.y, hv.z, hv.w};
            #pragma unroll
            for (int kk = 0; kk < 4; ++kk) {
                acc[i].x = fmaf(hs[kk], w[kk].x, acc[i].x);
                acc[i].y = fmaf(hs[kk], w[kk].y, acc[i].y);
                acc[i].z = fmaf(hs[kk], w[kk].z, acc[i].z);
                acc[i].w = fmaf(hs[kk], w[kk].w, acc[i].w);
            }
        }
    }

    #pragma unroll
    for (int i = 0; i < 4; ++i) {
        int row = row0 + rq * 4 + i;
        if (row < n)
            *(float4*)&out[(size_t)row * CH + cg * 4] = acc[i];
    }
}

// ---------------- bucket histogram (LDS-staged) ----------------
__global__ __launch_bounds__(256) void bucket_hist(
    const int* __restrict__ dst, int* __restrict__ bcnt, int E, int NB)
{
    __shared__ int h[NB_MAX];
    for (int i = threadIdx.x; i < NB; i += 256) h[i] = 0;
    __syncthreads();
    for (int i = blockIdx.x * 256 + threadIdx.x; i < E; i += gridDim.x * 256)
        atomicAdd(&h[dst[i] >> 7], 1);
    __syncthreads();
    for (int i = threadIdx.x; i < NB; i += 256) {
        int v = h[i];
        if (v) atomicAdd(&bcnt[i], v);
    }
}

// ---------------- single-block exclusive scan over NB (<=1024) counts ----------------
__global__ __launch_bounds__(256) void bucket_scan(
    const int* __restrict__ bcnt, int* __restrict__ boff,
    int* __restrict__ cursor, int NB)
{
    __shared__ int tsum[256];
    int t = threadIdx.x;
    int base = t * 4;
    int c[4];
    #pragma unroll
    for (int j = 0; j < 4; ++j) {
        int i = base + j;
        c[j] = (i < NB) ? bcnt[i] : 0;
    }
    int local = c[0] + c[1] + c[2] + c[3];
    tsum[t] = local;
    __syncthreads();
    for (int off = 1; off < 256; off <<= 1) {
        int v = (t >= off) ? tsum[t - off] : 0;
        __syncthreads();
        tsum[t] += v;
        __syncthreads();
    }
    int p = tsum[t] - local;
    #pragma unroll
    for (int j = 0; j < 4; ++j) {
        int i = base + j;
        if (i < NB) { boff[i] = p; cursor[i * CUR_PAD] = p; }
        p += c[j];
    }
    if (t == 255) boff[NB] = tsum[255];
}

// ---------------- block-aggregated scatter into bucket-major packed list ----------------
// packed = ((dst & 127) << 17) | src     (src < 2^17)
// Per block: LDS hist of its chunk -> ONE global atomic per (block,bucket)
// reserving a contiguous run (cursors line-padded) -> LDS-cursor placement.
__global__ __launch_bounds__(256) void bucket_scatter_blk(
    const int* __restrict__ src, const int* __restrict__ dst,
    int* __restrict__ cursor, int* __restrict__ bucketed, int E, int NB)
{
    __shared__ int hist[NB_MAX];
    __shared__ int rbase[NB_MAX];
    __shared__ int lcur[NB_MAX];

    const int t = threadIdx.x;
    const int s = blockIdx.x * SCAT_CHUNK;
    const int e = min(s + SCAT_CHUNK, E);

    for (int i = t; i < NB; i += 256) hist[i] = 0;
    __syncthreads();

    for (int i = s + t; i < e; i += 256)
        atomicAdd(&hist[dst[i] >> 7], 1);
    __syncthreads();

    for (int i = t; i < NB; i += 256) {
        int c = hist[i];
        rbase[i] = c ? atomicAdd(&cursor[i * CUR_PAD], c) : 0;
        lcur[i] = 0;
    }
    __syncthreads();

    for (int i = s + t; i < e; i += 256) {
        int d = dst[i];
        int b = d >> 7;
        int p = atomicAdd(&lcur[b], 1);
        bucketed[rbase[b] + p] = ((d & 127) << 17) | src[i];
    }
}

// ---------------- per-bucket counting sort -> per-node CSR segments ----------------
__global__ __launch_bounds__(256) void node_sort(
    const int* __restrict__ bucketed, const int* __restrict__ boff,
    int* __restrict__ sorted_src, int2* __restrict__ seg, int N)
{
    __shared__ int cnt[BNODES];
    __shared__ int sc[BNODES];
    __shared__ int cur[BNODES];
    const int bk = blockIdx.x;
    const int t  = threadIdx.x;
    const int s  = boff[bk];
    const int e  = boff[bk + 1];

    if (t < BNODES) cnt[t] = 0;
    __syncthreads();
    for (int i = s + t; i < e; i += 256)
        atomicAdd(&cnt[((unsigned)bucketed[i]) >> 17], 1);
    __syncthreads();

    if (t < BNODES) sc[t] = cnt[t];
    __syncthreads();
    for (int o = 1; o < BNODES; o <<= 1) {
        int v = (t < BNODES && t >= o) ? sc[t - o] : 0;
        __syncthreads();
        if (t < BNODES) sc[t] += v;
        __syncthreads();
    }
    if (t < BNODES) {
        int excl = sc[t] - cnt[t];
        cur[t] = excl;
        int node = bk * BNODES + t;
        if (node < N) seg[node] = make_int2(s + excl, cnt[t]);
    }
    __syncthreads();

    for (int i = s + t; i < e; i += 256) {
        int p = bucketed[i];
        int d = ((unsigned)p) >> 17;
        int pos = atomicAdd(&cur[d], 1);
        sorted_src[s + pos] = p & 0x1FFFF;
    }
}

// ---------------- aggregate: out[d][c] = b[c] + sum_{e in seg(d)} hw[src[e]][c] ----------------
__global__ __launch_bounds__(256) void aggregate_kernel(
    const float* __restrict__ hw, const int* __restrict__ sorted_src,
    const int2* __restrict__ seg, const float* __restrict__ bias,
    float* __restrict__ out, int N)
{
    const int lane = threadIdx.x & 63;
    const int node = blockIdx.x * 4 + (threadIdx.x >> 6);
    if (node >= N) return;

    int2 sc   = seg[node];
    int  base = sc.x;
    int  rem  = sc.y;

    float a[8];
    a[0] = bias[lane];
    #pragma unroll
    for (int i = 1; i < 8; ++i) a[i] = 0.f;

    while (rem > 0) {
        int take = rem < 64 ? rem : 64;
        int my = (lane < take) ? sorted_src[base + lane] : 0;
        int j = 0;
        for (; j + 8 <= take; j += 8) {
            int idx[8];
            #pragma unroll
            for (int u = 0; u < 8; ++u) idx[u] = __shfl(my, j + u);
            #pragma unroll
            for (int u = 0; u < 8; ++u)
                a[u] += hw[(size_t)idx[u] * CH + lane];
        }
        for (; j < take; ++j)
            a[0] += hw[(size_t)__shfl(my, j) * CH + lane];
        base += take;
        rem  -= take;
    }

    float r = ((a[0] + a[1]) + (a[2] + a[3])) + ((a[4] + a[5]) + (a[6] + a[7]));
    out[(size_t)node * CH + lane] = r;
}

extern "C" void kernel_launch(void* const* d_in, const int* in_sizes, int n_in,
                              void* d_out, int out_size, void* d_ws, size_t ws_size,
                              hipStream_t stream) {
    const float* x    = (const float*)d_in[0];
    const int*   esrc = (const int*)  d_in[1];
    const int*   edst = (const int*)  d_in[2];
    const float* W1   = (const float*)d_in[3];
    const float* b1   = (const float*)d_in[4];
    const float* W2   = (const float*)d_in[5];
    const float* b2   = (const float*)d_in[6];
    const float* W3   = (const float*)d_in[7];
    const float* b3   = (const float*)d_in[8];
    float* out = (float*)d_out;

    const int N  = in_sizes[0] / 128;
    const int E  = in_sizes[1];
    const int NB = (N + BNODES - 1) / BNODES;   // 782 for N=100000

    // workspace layout (~39.7 MB)
    char* ws = (char*)d_ws;
    float* buf0       = (float*)ws;  ws += (size_t)N * CH * 4;   // hw
    int*   bucketed   = (int*)ws;    ws += (size_t)E * 4;
    int*   sorted_src = (int*)ws;    ws += (size_t)E * 4;
    int2*  seg        = (int2*)ws;   ws += (size_t)N * 8;
    int*   bcnt       = (int*)ws;    ws += (size_t)NB * 4;
    int*   boff       = (int*)ws;    ws += (size_t)(NB + 1) * 4;
    // align cursor to 64 B
    ws = (char*)(((uintptr_t)ws + 63) & ~(uintptr_t)63);
    int*   cursor     = (int*)ws;    ws += (size_t)NB * CUR_PAD * 4;

    dim3 blk(256);
    int gemmGrid = (N + 63) / 64;
    int aggGrid  = (N + 3) / 4;
    int scatGrid = (E + SCAT_CHUNK - 1) / SCAT_CHUNK;

    // ---- CSR build via buckets (once; shared by all 3 layers) ----
    hipMemsetAsync(bcnt, 0, (size_t)NB * 4, stream);
    bucket_hist<<<256, blk, 0, stream>>>(edst, bcnt, E, NB);
    bucket_scan<<<1, blk, 0, stream>>>(bcnt, boff, cursor, NB);
    bucket_scatter_blk<<<scatGrid, blk, 0, stream>>>(esrc, edst, cursor, bucketed, E, NB);
    node_sort<<<NB, blk, 0, stream>>>(bucketed, boff, sorted_src, seg, N);

    // ---- layer 1 ----
    gemm_kernel<128, false><<<gemmGrid, blk, 0, stream>>>(x, W1, buf0, N);
    aggregate_kernel<<<aggGrid, blk, 0, stream>>>(buf0, sorted_src, seg, b1, out, N);
    // ---- layer 2 (relu fused into gemm load) ----
    gemm_kernel<64, true><<<gemmGrid, blk, 0, stream>>>(out, W2, buf0, N);
    aggregate_kernel<<<aggGrid, blk, 0, stream>>>(buf0, sorted_src, seg, b2, out, N);
    // ---- layer 3 ----
    gemm_kernel<64, true><<<gemmGrid, blk, 0, stream>>>(out, W3, buf0, N);
    aggregate_kernel<<<aggGrid, blk, 0, stream>>>(buf0, sorted_src, seg, b3, out, N);
}